// Round 2
// baseline (802.360 us; speedup 1.0000x reference)
//
#include <hip/hip_runtime.h>

typedef __attribute__((ext_vector_type(8))) __bf16 bf16x8;
typedef __attribute__((ext_vector_type(4))) __bf16 bf16x4;
typedef __attribute__((ext_vector_type(4))) float f32x4;

#define SEQ 1024
#define NH 32
#define PD 64
#define ND 128
#define CLEN 64
#define NCHUNK 16

// LDS row strides (elements); strides keep 16B alignment for b128 reads and
// 272B (=17*16) row pitch so 16-row column reads spread over all bank slots.
#define BS_LD 136   // B staged row-major (s-major) [64][136] bf16  -> phase (a)
#define BT_LD 72    // B staged transposed (n-major) [128][72] bf16 -> phase (c)
#define XT_LD 72    // X transposed (p-major) [64][72] bf16         -> phases (b),(c)
#define SS_LD 72    // S (masked/decayed) row-major [64][72] bf16
#define SR_LD 136   // running-state bf16 mirror [64][136]

// XOR swizzle for BsT/XsT in-row index (breaks the staging-scatter and the
// strided-read conflicts; 8-element-aligned so b128 reads stay legal).
__device__ __forceinline__ int swz(int r) { return ((r >> 2) & 7) << 3; }

// LDS-only barrier: lgkmcnt drain + s_barrier, NO vmcnt drain -> global-load
// prefetch (B/X for c+1, C-frags) stays in flight across all barriers.
__device__ __forceinline__ void barrier_lds() {
    asm volatile("s_waitcnt lgkmcnt(0)" ::: "memory");
    __builtin_amdgcn_s_barrier();
    asm volatile("" ::: "memory");
}

__global__ __launch_bounds__(512, 4)   // force VGPR<=128 so 2 blocks/CU is guaranteed
void ssd_fused(const float* __restrict__ Xg, const float* __restrict__ Ag,
               const float* __restrict__ Bg, const float* __restrict__ Cg,
               float* __restrict__ Yg)
{
    __shared__ __align__(16) float cumA[64];
    __shared__ __align__(16) float eA[64];
    __shared__ __align__(16) float dxA[64];
    __shared__ __align__(16) float scal[4];
    __shared__ __align__(16) __bf16 Bs [64 * BS_LD];
    __shared__ __align__(16) __bf16 BsT[128 * BT_LD];
    __shared__ __align__(16) __bf16 XsT[64 * XT_LD];
    __shared__ __align__(16) __bf16 Ss [64 * SS_LD];
    __shared__ __align__(16) __bf16 SrB[64 * SR_LD];
    // total ~72.5 KB -> 2 blocks/CU

    const int tid  = threadIdx.x;
    const int w    = tid >> 6;
    const int lane = tid & 63;
    const int q    = lane >> 4;   // quad within wave
    const int ln   = lane & 15;
    const int m4   = w & 3;       // M-strip (rows 16*m4..+15)
    const int h2   = w >> 2;      // half split for N tiles

    const int bh = blockIdx.x;
    const int b  = bh >> 5;
    const int h  = bh & 31;

    const float* Xb = Xg + (size_t)b * SEQ * NH * PD + (size_t)h * PD;
    const float* Ab = Ag + (size_t)b * SEQ * NH + h;
    const float* Bb = Bg + (size_t)b * SEQ * NH * ND + (size_t)h * ND;
    const float* Cb = Cg + (size_t)b * SEQ * NH * ND + (size_t)h * ND;
    float*       Yb = Yg + (size_t)b * SEQ * NH * PD + (size_t)h * PD;

    const int arow = 16 * m4 + ln;   // output row of this lane; also C-frag row

    // zero the bf16 state mirror (read by phase (d) in chunk 0)
    {
        unsigned int* p0 = (unsigned int*)SrB;
        for (int i = tid; i < 64 * SR_LD / 2; i += 512) p0[i] = 0u;
    }
    f32x4 srun[4];
    #pragma unroll
    for (int t = 0; t < 4; ++t) srun[t] = (f32x4){0.f, 0.f, 0.f, 0.f};

    f32x4 breg[4], xreg[2];
    float areg = 0.f;
    f32x4 cf32[8];      // raw C fragment (f32), prefetched one chunk ahead
    bf16x8 cfrag[4];    // converted C fragment, used by phases (a) and (d)

    // ---- B/X/A cooperative loads (block-distributed, coalesced) ----
    #define LOADBX(S0) do {                                                       \
        _Pragma("unroll")                                                         \
        for (int i = 0; i < 4; ++i) {                                             \
            int v   = tid + 512 * i;                                              \
            int row = v >> 5;                                                     \
            int c4  = (v & 31) << 2;                                              \
            breg[i] = *(const f32x4*)(Bb + (size_t)((S0) + row) * (NH * ND) + c4);\
        }                                                                         \
        _Pragma("unroll")                                                         \
        for (int i = 0; i < 2; ++i) {                                             \
            int v   = tid + 512 * i;                                              \
            int row = v >> 4;                                                     \
            int c4  = (v & 15) << 2;                                              \
            xreg[i] = *(const f32x4*)(Xb + (size_t)((S0) + row) * (NH * PD) + c4);\
        }                                                                         \
        if (w == 0) areg = Ab[(size_t)((S0) + lane) * NH];                        \
    } while (0)

    // ---- C fragment loads (per-wave; h2-twin waves duplicate -> L2 hit) ----
    #define LOADC(S0) do {                                                        \
        _Pragma("unroll")                                                         \
        for (int kt = 0; kt < 4; ++kt) {                                          \
            const float* p = Cb + (size_t)((S0) + arow) * (NH * ND) + kt * 32 + q * 8; \
            cf32[2 * kt]     = *(const f32x4*)(p);                                \
            cf32[2 * kt + 1] = *(const f32x4*)(p + 4);                            \
        }                                                                         \
    } while (0)

    // ---- stage prefetched B/X regs -> LDS ----
    #define STAGE() do {                                                          \
        _Pragma("unroll")                                                         \
        for (int i = 0; i < 4; ++i) {                                             \
            int v   = tid + 512 * i;                                              \
            int row = v >> 5;                                                     \
            int c4  = (v & 31) << 2;                                              \
            bf16x4 bv;                                                            \
            bv[0] = (__bf16)breg[i][0]; bv[1] = (__bf16)breg[i][1];               \
            bv[2] = (__bf16)breg[i][2]; bv[3] = (__bf16)breg[i][3];               \
            *(bf16x4*)&Bs[row * BS_LD + c4] = bv;                                 \
            _Pragma("unroll")                                                     \
            for (int j = 0; j < 4; ++j) {                                         \
                int n = c4 + j;                                                   \
                BsT[n * BT_LD + (row ^ swz(n))] = bv[j];                          \
            }                                                                     \
        }                                                                         \
        _Pragma("unroll")                                                         \
        for (int i = 0; i < 2; ++i) {                                             \
            int v   = tid + 512 * i;                                              \
            int row = v >> 4;                                                     \
            int c4  = (v & 15) << 2;                                              \
            _Pragma("unroll")                                                     \
            for (int j = 0; j < 4; ++j) {                                         \
                int p = c4 + j;                                                   \
                XsT[p * XT_LD + (row ^ swz(p))] = (__bf16)xreg[i][j];             \
            }                                                                     \
        }                                                                         \
    } while (0)

    // ---- wave 0: inclusive scan of A over the chunk ----
    #define SCAN() do {                                                           \
        if (w == 0) {                                                             \
            float v = areg;                                                       \
            _Pragma("unroll")                                                     \
            for (int off = 1; off < 64; off <<= 1) {                              \
                float u = __shfl_up(v, off, 64);                                  \
                if (lane >= off) v += u;                                          \
            }                                                                     \
            float alast = __shfl(v, 63, 64);                                      \
            cumA[lane] = v;                                                       \
            eA[lane]   = __expf(v);            /* state_decay_out */              \
            dxA[lane]  = __expf(alast - v);    /* decay_states   */               \
            if (lane == 0) scal[0] = __expf(alast);                               \
        }                                                                         \
    } while (0)

    // prologue: chunk 0 loads + stage + scan (visibility covered by S1 below)
    LOADBX(0);
    LOADC(0);
    STAGE();
    SCAN();

    for (int c = 0; c < NCHUNK; ++c) {
        const int s0 = c * CLEN;

        barrier_lds();  // S1: staged tiles(c) + scan(c) + SrB(c-1) visible

        // register the per-chunk scalars now (scan(c+1) overwrites them post-S3)
        const float elast = scal[0];
        const f32x4 ev = *(const f32x4*)&eA[16 * m4 + 4 * q];
        const f32x4 ca = *(const f32x4*)&cumA[16 * m4 + 4 * q];

        // prefetch B/X/A for c+1 (consumed by STAGE at the end of this chunk)
        if (c + 1 < NCHUNK) LOADBX((c + 1) * CLEN);

        // convert this chunk's C fragment (vmcnt wait hits only the C loads)
        #pragma unroll
        for (int kt = 0; kt < 4; ++kt) {
            bf16x8 f;
            #pragma unroll
            for (int j = 0; j < 4; ++j) {
                f[j]     = (__bf16)cf32[2 * kt][j];
                f[4 + j] = (__bf16)cf32[2 * kt + 1][j];
            }
            cfrag[kt] = f;
        }

        // ---------------- (a): S = tril-decay(C @ B^T) -> Ss ----------------
        // B-frag now a contiguous b128 read from row-major Bs (gather removed)
        {
            #pragma unroll
            for (int t = 0; t < 2; ++t) {
                const int sn   = 2 * h2 + t;
                const int scol = 16 * sn + ln;
                if (sn <= m4) {
                    f32x4 acc = (f32x4){0.f, 0.f, 0.f, 0.f};
                    #pragma unroll
                    for (int kt = 0; kt < 4; ++kt) {
                        bf16x8 bq = *(const bf16x8*)&Bs[scol * BS_LD + kt * 32 + q * 8];
                        acc = __builtin_amdgcn_mfma_f32_16x16x32_bf16(cfrag[kt], bq, acc, 0, 0, 0);
                    }
                    float csc = cumA[scol];
                    #pragma unroll
                    for (int r = 0; r < 4; ++r) {
                        int lrow  = 16 * m4 + 4 * q + r;
                        float val = (lrow >= scol) ? acc[r] * __expf(ca[r] - csc) : 0.f;
                        Ss[lrow * SS_LD + scol] = (__bf16)val;
                    }
                } else {
                    #pragma unroll
                    for (int r = 0; r < 4; ++r)
                        Ss[(16 * m4 + 4 * q + r) * SS_LD + scol] = (__bf16)0.f;
                }
            }
        }

        // ---------------- (d): yoff = C @ S_run^T (eA folded in epilogue) ----
        f32x4 yoff[2];
        yoff[0] = (f32x4){0.f, 0.f, 0.f, 0.f};
        yoff[1] = (f32x4){0.f, 0.f, 0.f, 0.f};
        #pragma unroll
        for (int kt = 0; kt < 4; ++kt) {
            #pragma unroll
            for (int t = 0; t < 2; ++t) {
                int pt = 2 * h2 + t;
                bf16x8 bq = *(const bf16x8*)&SrB[(16 * pt + ln) * SR_LD + kt * 32 + q * 8];
                yoff[t] = __builtin_amdgcn_mfma_f32_16x16x32_bf16(cfrag[kt], bq, yoff[t], 0, 0, 0);
            }
        }

        // ---------------- (c): states = (X^T * dexp) @ B ---------------------
        f32x4 sacc[4];
        #pragma unroll
        for (int t = 0; t < 4; ++t) sacc[t] = (f32x4){0.f, 0.f, 0.f, 0.f};
        {
            const int prow = arow;
            #pragma unroll
            for (int kt = 0; kt < 2; ++kt) {
                bf16x8 xv = *(const bf16x8*)&XsT[prow * XT_LD + ((kt * 32 + q * 8) ^ swz(prow))];
                f32x4 d0 = *(const f32x4*)&dxA[kt * 32 + q * 8];
                f32x4 d1 = *(const f32x4*)&dxA[kt * 32 + q * 8 + 4];
                bf16x8 af;
                #pragma unroll
                for (int j = 0; j < 4; ++j) {
                    af[j]     = (__bf16)((float)xv[j] * d0[j]);
                    af[4 + j] = (__bf16)((float)xv[4 + j] * d1[j]);
                }
                #pragma unroll
                for (int t = 0; t < 4; ++t) {
                    int nrow = 16 * (4 * h2 + t) + ln;
                    bf16x8 bq = *(const bf16x8*)&BsT[nrow * BT_LD + ((kt * 32 + q * 8) ^ swz(nrow))];
                    sacc[t] = __builtin_amdgcn_mfma_f32_16x16x32_bf16(af, bq, sacc[t], 0, 0, 0);
                }
            }
        }

        barrier_lds();  // S2: Ss visible (its write drain hid under (d),(c))

        // prefetch C fragment for c+1 (cf32 dead since the convert above;
        // latency covered by (b) + epilogue + staging + S1)
        if (c + 1 < NCHUNK) LOADC((c + 1) * CLEN);

        // ---------------- (b): yacc = S' @ X, then fold yoff -----------------
        f32x4 yacc[2];
        yacc[0] = (f32x4){0.f, 0.f, 0.f, 0.f};
        yacc[1] = (f32x4){0.f, 0.f, 0.f, 0.f};
        {
            // K-steps above the diagonal strip are entirely zero -> skip
            for (int kt = 0; kt <= (m4 >> 1); ++kt) {
                bf16x8 af = *(const bf16x8*)&Ss[arow * SS_LD + kt * 32 + q * 8];
                #pragma unroll
                for (int t = 0; t < 2; ++t) {
                    int prow = 16 * (2 * h2 + t) + ln;
                    bf16x8 bq = *(const bf16x8*)&XsT[prow * XT_LD + ((kt * 32 + q * 8) ^ swz(prow))];
                    yacc[t] = __builtin_amdgcn_mfma_f32_16x16x32_bf16(af, bq, yacc[t], 0, 0, 0);
                }
            }
            #pragma unroll
            for (int t = 0; t < 2; ++t)
                #pragma unroll
                for (int r = 0; r < 4; ++r)
                    yacc[t][r] += ev[r] * yoff[t][r];
        }

        barrier_lds();  // S3: all LDS reads of chunk c done

        // ---------------- state update + SrB refresh + Y store ---------------
        {
            #pragma unroll
            for (int t = 0; t < 4; ++t) {
                int ncol = 16 * (4 * h2 + t) + ln;
                #pragma unroll
                for (int r = 0; r < 4; ++r) {
                    float s = elast * srun[t][r] + sacc[t][r];
                    srun[t][r] = s;
                    SrB[(16 * m4 + 4 * q + r) * SR_LD + ncol] = (__bf16)s;
                }
            }
            #pragma unroll
            for (int t = 0; t < 2; ++t) {
                int pcol = 16 * (2 * h2 + t) + ln;
                #pragma unroll
                for (int r = 0; r < 4; ++r) {
                    int lrow = 16 * m4 + 4 * q + r;
                    Yb[(size_t)(s0 + lrow) * (NH * PD) + pcol] = yacc[t][r];
                }
            }
        }

        // stage c+1 (visibility covered by next S1); scan(c+1) writes the
        // scalar buffers — all chunk-c readers registered them post-S1
        if (c + 1 < NCHUNK) {
            STAGE();
            SCAN();
        }
    }
    #undef LOADBX
    #undef LOADC
    #undef STAGE
    #undef SCAN
}

extern "C" void kernel_launch(void* const* d_in, const int* in_sizes, int n_in,
                              void* d_out, int out_size, void* d_ws, size_t ws_size,
                              hipStream_t stream) {
    const float* X = (const float*)d_in[0];
    const float* A = (const float*)d_in[1];
    const float* B = (const float*)d_in[2];
    const float* C = (const float*)d_in[3];
    float* Y = (float*)d_out;
    dim3 grid(512, 1, 1), block(512, 1, 1);
    hipLaunchKernelGGL(ssd_fused, grid, block, 0, stream, X, A, B, C, Y);
}

// Round 3
// 639.840 us; speedup vs baseline: 1.2540x; 1.2540x over previous
//
#include <hip/hip_runtime.h>

typedef __attribute__((ext_vector_type(8))) __bf16 bf16x8;
typedef __attribute__((ext_vector_type(4))) __bf16 bf16x4;
typedef __attribute__((ext_vector_type(4))) float f32x4;

#define SEQ 1024
#define NH 32
#define PD 64
#define ND 128
#define CLEN 64
#define NCHUNK 16

// LDS row strides (elements); strides keep 16B alignment for b128 reads and
// 272B (=17*16) row pitch so 16-row column reads spread over all bank slots.
#define BS_LD 136   // B staged row-major (s-major) [64][136] bf16  -> phase (a)
#define BT_LD 72    // B staged transposed (n-major) [128][72] bf16 -> phase (c)
#define XT_LD 72    // X transposed (p-major) [64][72] bf16         -> phases (b),(c)
#define SS_LD 72    // S (masked/decayed) row-major [64][72] bf16
#define SR_LD 136   // running-state bf16 mirror [64][136]

// XOR swizzle for BsT/XsT in-row index: spreads the 2B transpose-scatter
// writes from 32-way to ~8-way bank conflicts; reads stay conflict-free
// (verified by bank arithmetic: read groups still cover all 8 4-bank slots).
__device__ __forceinline__ int swz(int r) { return ((r >> 2) & 7) << 3; }

// LDS-only barrier: lgkmcnt drain + s_barrier, NO vmcnt drain -> global-load
// prefetch (B/X for c+1, C-frags) stays in flight across all barriers.
__device__ __forceinline__ void barrier_lds() {
    asm volatile("s_waitcnt lgkmcnt(0)" ::: "memory");
    __builtin_amdgcn_s_barrier();
    asm volatile("" ::: "memory");
}

__global__ __launch_bounds__(512, 2)   // VGPR budget 256; aim <=128 total for 2 blk/CU
void ssd_fused(const float* __restrict__ Xg, const float* __restrict__ Ag,
               const float* __restrict__ Bg, const float* __restrict__ Cg,
               float* __restrict__ Yg)
{
    __shared__ __align__(16) float cumA[64];
    __shared__ __align__(16) float eA[64];
    __shared__ __align__(16) float dxA[64];
    __shared__ __align__(16) float scal[4];
    __shared__ __align__(16) __bf16 Bs [64 * BS_LD];
    __shared__ __align__(16) __bf16 BsT[128 * BT_LD];
    __shared__ __align__(16) __bf16 XsT[64 * XT_LD];
    __shared__ __align__(16) __bf16 Ss [64 * SS_LD];
    __shared__ __align__(16) __bf16 SrB[64 * SR_LD];
    // total ~72.5 KB -> 2 blocks/CU by LDS

    const int tid  = threadIdx.x;
    const int w    = tid >> 6;
    const int lane = tid & 63;
    const int q    = lane >> 4;   // quad within wave
    const int ln   = lane & 15;
    const int m4   = w & 3;       // M-strip (rows 16*m4..+15)
    const int h2   = w >> 2;      // half split for N tiles

    const int bh = blockIdx.x;
    const int b  = bh >> 5;
    const int h  = bh & 31;

    const float* Xb = Xg + (size_t)b * SEQ * NH * PD + (size_t)h * PD;
    const float* Ab = Ag + (size_t)b * SEQ * NH + h;
    const float* Bb = Bg + (size_t)b * SEQ * NH * ND + (size_t)h * ND;
    const float* Cb = Cg + (size_t)b * SEQ * NH * ND + (size_t)h * ND;
    float*       Yb = Yg + (size_t)b * SEQ * NH * PD + (size_t)h * PD;

    const int arow = 16 * m4 + ln;   // output row of this lane; also C-frag row

    // zero the bf16 state mirror (read by phase (d) in chunk 0)
    {
        unsigned int* p0 = (unsigned int*)SrB;
        for (int i = tid; i < 64 * SR_LD / 2; i += 512) p0[i] = 0u;
    }
    f32x4 srun[4];
    #pragma unroll
    for (int t = 0; t < 4; ++t) srun[t] = (f32x4){0.f, 0.f, 0.f, 0.f};

    f32x4 breg[4], xreg[2];
    float areg = 0.f;
    f32x4 cf32[8];      // raw C fragment (f32); short-lived (tail -> next loop top)

    // ---- B/X/A cooperative loads (block-distributed, coalesced) ----
    #define LOADBX(S0) do {                                                       \
        _Pragma("unroll")                                                         \
        for (int i = 0; i < 4; ++i) {                                             \
            int v   = tid + 512 * i;                                              \
            int row = v >> 5;                                                     \
            int c4  = (v & 31) << 2;                                              \
            breg[i] = *(const f32x4*)(Bb + (size_t)((S0) + row) * (NH * ND) + c4);\
        }                                                                         \
        _Pragma("unroll")                                                         \
        for (int i = 0; i < 2; ++i) {                                             \
            int v   = tid + 512 * i;                                              \
            int row = v >> 4;                                                     \
            int c4  = (v & 15) << 2;                                              \
            xreg[i] = *(const f32x4*)(Xb + (size_t)((S0) + row) * (NH * PD) + c4);\
        }                                                                         \
        if (w == 0) areg = Ab[(size_t)((S0) + lane) * NH];                        \
    } while (0)

    // ---- C fragment loads (per-wave; h2-twin waves duplicate -> L2 hit) ----
    #define LOADC(S0) do {                                                        \
        _Pragma("unroll")                                                         \
        for (int kt = 0; kt < 4; ++kt) {                                          \
            const float* p = Cb + (size_t)((S0) + arow) * (NH * ND) + kt * 32 + q * 8; \
            cf32[2 * kt]     = *(const f32x4*)(p);                                \
            cf32[2 * kt + 1] = *(const f32x4*)(p + 4);                            \
        }                                                                         \
    } while (0)

    // ---- stage prefetched B/X regs -> LDS ----
    #define STAGE() do {                                                          \
        _Pragma("unroll")                                                         \
        for (int i = 0; i < 4; ++i) {                                             \
            int v   = tid + 512 * i;                                              \
            int row = v >> 5;                                                     \
            int c4  = (v & 31) << 2;                                              \
            bf16x4 bv;                                                            \
            bv[0] = (__bf16)breg[i][0]; bv[1] = (__bf16)breg[i][1];               \
            bv[2] = (__bf16)breg[i][2]; bv[3] = (__bf16)breg[i][3];               \
            *(bf16x4*)&Bs[row * BS_LD + c4] = bv;                                 \
            _Pragma("unroll")                                                     \
            for (int j = 0; j < 4; ++j) {                                         \
                int n = c4 + j;                                                   \
                BsT[n * BT_LD + (row ^ swz(n))] = bv[j];                          \
            }                                                                     \
        }                                                                         \
        _Pragma("unroll")                                                         \
        for (int i = 0; i < 2; ++i) {                                             \
            int v   = tid + 512 * i;                                              \
            int row = v >> 4;                                                     \
            int c4  = (v & 15) << 2;                                              \
            _Pragma("unroll")                                                     \
            for (int j = 0; j < 4; ++j) {                                         \
                int p = c4 + j;                                                   \
                XsT[p * XT_LD + (row ^ swz(p))] = (__bf16)xreg[i][j];             \
            }                                                                     \
        }                                                                         \
    } while (0)

    // ---- wave 0: inclusive scan of A over the chunk ----
    #define SCAN() do {                                                           \
        if (w == 0) {                                                             \
            float v = areg;                                                       \
            _Pragma("unroll")                                                     \
            for (int off = 1; off < 64; off <<= 1) {                              \
                float u = __shfl_up(v, off, 64);                                  \
                if (lane >= off) v += u;                                          \
            }                                                                     \
            float alast = __shfl(v, 63, 64);                                      \
            cumA[lane] = v;                                                       \
            eA[lane]   = __expf(v);            /* state_decay_out */              \
            dxA[lane]  = __expf(alast - v);    /* decay_states   */               \
            if (lane == 0) scal[0] = __expf(alast);                               \
        }                                                                         \
    } while (0)

    // prologue: chunk 0 loads + stage + scan (visibility covered by S1 below)
    LOADBX(0);
    LOADC(0);
    STAGE();
    SCAN();

    for (int c = 0; c < NCHUNK; ++c) {
        const int s0 = c * CLEN;

        barrier_lds();  // S1: staged tiles(c) + scan(c) + SrB(c-1) visible

        // register the per-chunk scalars now (scan(c+1) overwrites them post-S3)
        const float elast = scal[0];
        const f32x4 ev = *(const f32x4*)&eA[16 * m4 + 4 * q];
        const f32x4 ca = *(const f32x4*)&cumA[16 * m4 + 4 * q];

        // prefetch B/X/A for c+1 (consumed by STAGE at the tail of this chunk)
        if (c + 1 < NCHUNK) LOADBX((c + 1) * CLEN);

        // convert this chunk's C fragment; cf32 dies here (short live range).
        // vmcnt wait here covers only the C loads (LOADBX is younger).
        bf16x8 cA[4];
        #pragma unroll
        for (int kt = 0; kt < 4; ++kt) {
            bf16x8 f;
            #pragma unroll
            for (int j = 0; j < 4; ++j) {
                f[j]     = (__bf16)cf32[2 * kt][j];
                f[4 + j] = (__bf16)cf32[2 * kt + 1][j];
            }
            cA[kt] = f;
        }

        // ---------------- (a): S = tril-decay(C @ B^T) -> Ss ----------------
        {
            #pragma unroll
            for (int t = 0; t < 2; ++t) {
                const int sn   = 2 * h2 + t;
                const int scol = 16 * sn + ln;
                if (sn <= m4) {
                    f32x4 acc = (f32x4){0.f, 0.f, 0.f, 0.f};
                    #pragma unroll
                    for (int kt = 0; kt < 4; ++kt) {
                        bf16x8 bq = *(const bf16x8*)&Bs[scol * BS_LD + kt * 32 + q * 8];
                        acc = __builtin_amdgcn_mfma_f32_16x16x32_bf16(cA[kt], bq, acc, 0, 0, 0);
                    }
                    float csc = cumA[scol];
                    #pragma unroll
                    for (int r = 0; r < 4; ++r) {
                        int lrow  = 16 * m4 + 4 * q + r;
                        float val = (lrow >= scol) ? acc[r] * __expf(ca[r] - csc) : 0.f;
                        Ss[lrow * SS_LD + scol] = (__bf16)val;
                    }
                } else {
                    #pragma unroll
                    for (int r = 0; r < 4; ++r)
                        Ss[(16 * m4 + 4 * q + r) * SS_LD + scol] = (__bf16)0.f;
                }
            }
        }

        // ---------------- (d): yoff = C @ S_run^T (eA folded in epilogue) ----
        f32x4 yoff[2];
        yoff[0] = (f32x4){0.f, 0.f, 0.f, 0.f};
        yoff[1] = (f32x4){0.f, 0.f, 0.f, 0.f};
        #pragma unroll
        for (int kt = 0; kt < 4; ++kt) {
            #pragma unroll
            for (int t = 0; t < 2; ++t) {
                int pt = 2 * h2 + t;
                bf16x8 bq = *(const bf16x8*)&SrB[(16 * pt + ln) * SR_LD + kt * 32 + q * 8];
                yoff[t] = __builtin_amdgcn_mfma_f32_16x16x32_bf16(cA[kt], bq, yoff[t], 0, 0, 0);
            }
        }
        // cA dead here

        // ---------------- (c): states = (X^T * dexp) @ B ---------------------
        f32x4 sacc[4];
        #pragma unroll
        for (int t = 0; t < 4; ++t) sacc[t] = (f32x4){0.f, 0.f, 0.f, 0.f};
        {
            #pragma unroll
            for (int kt = 0; kt < 2; ++kt) {
                bf16x8 xv = *(const bf16x8*)&XsT[arow * XT_LD + ((kt * 32 + q * 8) ^ swz(arow))];
                f32x4 d0 = *(const f32x4*)&dxA[kt * 32 + q * 8];
                f32x4 d1 = *(const f32x4*)&dxA[kt * 32 + q * 8 + 4];
                bf16x8 af;
                #pragma unroll
                for (int j = 0; j < 4; ++j) {
                    af[j]     = (__bf16)((float)xv[j] * d0[j]);
                    af[4 + j] = (__bf16)((float)xv[4 + j] * d1[j]);
                }
                #pragma unroll
                for (int t = 0; t < 4; ++t) {
                    int nrow = 16 * (4 * h2 + t) + ln;
                    bf16x8 bq = *(const bf16x8*)&BsT[nrow * BT_LD + ((kt * 32 + q * 8) ^ swz(nrow))];
                    sacc[t] = __builtin_amdgcn_mfma_f32_16x16x32_bf16(af, bq, sacc[t], 0, 0, 0);
                }
            }
        }

        barrier_lds();  // S2: Ss visible (its write drain hid under (d),(c))

        // ---------------- (b): yacc = S' @ X, then fold yoff -----------------
        f32x4 yacc[2];
        yacc[0] = (f32x4){0.f, 0.f, 0.f, 0.f};
        yacc[1] = (f32x4){0.f, 0.f, 0.f, 0.f};
        {
            // K-steps above the diagonal strip are entirely zero -> skip
            for (int kt = 0; kt <= (m4 >> 1); ++kt) {
                bf16x8 af = *(const bf16x8*)&Ss[arow * SS_LD + kt * 32 + q * 8];
                #pragma unroll
                for (int t = 0; t < 2; ++t) {
                    int prow = 16 * (2 * h2 + t) + ln;
                    bf16x8 bq = *(const bf16x8*)&XsT[prow * XT_LD + ((kt * 32 + q * 8) ^ swz(prow))];
                    yacc[t] = __builtin_amdgcn_mfma_f32_16x16x32_bf16(af, bq, yacc[t], 0, 0, 0);
                }
            }
            #pragma unroll
            for (int t = 0; t < 2; ++t)
                #pragma unroll
                for (int r = 0; r < 4; ++r)
                    yacc[t][r] += ev[r] * yoff[t][r];
        }

        barrier_lds();  // S3: all LDS reads of chunk c done

        // ---------------- state update + SrB refresh + Y store ---------------
        {
            #pragma unroll
            for (int t = 0; t < 4; ++t) {
                int ncol = 16 * (4 * h2 + t) + ln;
                #pragma unroll
                for (int r = 0; r < 4; ++r) {
                    float s = elast * srun[t][r] + sacc[t][r];
                    srun[t][r] = s;
                    SrB[(16 * m4 + 4 * q + r) * SR_LD + ncol] = (__bf16)s;
                }
            }
            #pragma unroll
            for (int t = 0; t < 2; ++t) {
                int pcol = 16 * (2 * h2 + t) + ln;
                #pragma unroll
                for (int r = 0; r < 4; ++r) {
                    int lrow = 16 * m4 + 4 * q + r;
                    Yb[(size_t)(s0 + lrow) * (NH * PD) + pcol] = yacc[t][r];
                }
            }
        }

        // tail: C prefetch for c+1 (short register lifetime: here -> next loop
        // top convert), then stage c+1 and scan (visibility via next S1).
        if (c + 1 < NCHUNK) {
            LOADC((c + 1) * CLEN);
            STAGE();
            SCAN();
        }
    }
    #undef LOADBX
    #undef LOADC
    #undef STAGE
    #undef SCAN
}

extern "C" void kernel_launch(void* const* d_in, const int* in_sizes, int n_in,
                              void* d_out, int out_size, void* d_ws, size_t ws_size,
                              hipStream_t stream) {
    const float* X = (const float*)d_in[0];
    const float* A = (const float*)d_in[1];
    const float* B = (const float*)d_in[2];
    const float* C = (const float*)d_in[3];
    float* Y = (float*)d_out;
    dim3 grid(512, 1, 1), block(512, 1, 1);
    hipLaunchKernelGGL(ssd_fused, grid, block, 0, stream, X, A, B, C, Y);
}